// Round 1
// baseline (1553.920 us; speedup 1.0000x reference)
//
#include <hip/hip_runtime.h>
#include <hip/hip_bf16.h>

#define B_ 256
#define T_ 512
#define I_ 128
#define H_ 256

// ---------- xw value type helpers (fp32 normally; bf16 fallback if ws small) ----
__device__ inline float xwt_to_float(float v) { return v; }
__device__ inline float xwt_to_float(__hip_bfloat16 v) { return __bfloat162float(v); }
__device__ inline void xwt_store(float* p, float v) { *p = v; }
__device__ inline void xwt_store(__hip_bfloat16* p, float v) { *p = __float2bfloat16(v); }

// =====================================================================
// Kernel 1: xw[m][j] = dot(x[m,0:128], W_ih[j,0:128]) + (b_ih[j]+b_hh[j])
//   m = b*T + t  (x is [B][T][I] so m directly indexes rows of x)
//   xw layout: [B][T][H] row-major -> WG b in kernel 2 reads a contiguous
//   512 KB slice sequentially (good L2 locality).
// Tiling: 128 (m) x 128 (j) block tile, K chunked by 32, 8x8 register tile.
// =====================================================================
template <typename XWT>
__global__ __launch_bounds__(256) void xw_gemm(const float* __restrict__ x,
                                               const float* __restrict__ W_ih,
                                               const float* __restrict__ b_ih,
                                               const float* __restrict__ b_hh,
                                               XWT* __restrict__ xw) {
    __shared__ float xs[128][33];   // +1 pad: rows ty+16i -> distinct banks
    __shared__ float wsm[128][33];

    const int bx = blockIdx.x;
    const int mb = bx >> 1;      // 0..1023
    const int nb = bx & 1;       // 0..1
    const int m0 = mb * 128;
    const int n0 = nb * 128;
    const int tid = (int)threadIdx.x;
    const int ty = tid >> 4;     // 0..15
    const int tx = tid & 15;     // 0..15

    float acc[8][8];
#pragma unroll
    for (int i = 0; i < 8; ++i)
#pragma unroll
        for (int j = 0; j < 8; ++j) acc[i][j] = 0.f;

    for (int kc = 0; kc < I_; kc += 32) {
        // Stage tiles: 2 threads per row, 16 floats each (4 x float4).
        {
            const int r  = tid >> 1;
            const int ks = (tid & 1) * 16;
            const float4* sx = reinterpret_cast<const float4*>(x + (size_t)(m0 + r) * I_ + kc + ks);
            float4 a0 = sx[0], a1 = sx[1], a2 = sx[2], a3 = sx[3];
            const float4* sw = reinterpret_cast<const float4*>(W_ih + (size_t)(n0 + r) * I_ + kc + ks);
            float4 b0 = sw[0], b1 = sw[1], b2 = sw[2], b3 = sw[3];
            float* dx = &xs[r][ks];
            dx[0]=a0.x; dx[1]=a0.y; dx[2]=a0.z; dx[3]=a0.w;
            dx[4]=a1.x; dx[5]=a1.y; dx[6]=a1.z; dx[7]=a1.w;
            dx[8]=a2.x; dx[9]=a2.y; dx[10]=a2.z; dx[11]=a2.w;
            dx[12]=a3.x; dx[13]=a3.y; dx[14]=a3.z; dx[15]=a3.w;
            float* dw = &wsm[r][ks];
            dw[0]=b0.x; dw[1]=b0.y; dw[2]=b0.z; dw[3]=b0.w;
            dw[4]=b1.x; dw[5]=b1.y; dw[6]=b1.z; dw[7]=b1.w;
            dw[8]=b2.x; dw[9]=b2.y; dw[10]=b2.z; dw[11]=b2.w;
            dw[12]=b3.x; dw[13]=b3.y; dw[14]=b3.z; dw[15]=b3.w;
        }
        __syncthreads();
#pragma unroll
        for (int k = 0; k < 32; ++k) {
            float a[8], bv[8];
#pragma unroll
            for (int i = 0; i < 8; ++i) a[i] = xs[ty + 16 * i][k];
#pragma unroll
            for (int j = 0; j < 8; ++j) bv[j] = wsm[tx + 16 * j][k];
#pragma unroll
            for (int i = 0; i < 8; ++i)
#pragma unroll
                for (int j = 0; j < 8; ++j) acc[i][j] = fmaf(a[i], bv[j], acc[i][j]);
        }
        __syncthreads();
    }

    float bias[8];
#pragma unroll
    for (int j = 0; j < 8; ++j) {
        const int n = n0 + tx + 16 * j;
        bias[j] = b_ih[n] + b_hh[n];
    }
#pragma unroll
    for (int i = 0; i < 8; ++i) {
        const size_t row = (size_t)(m0 + ty + 16 * i) * H_;
#pragma unroll
        for (int j = 0; j < 8; ++j) {
            xwt_store(&xw[row + n0 + tx + 16 * j], acc[i][j] + bias[j]);
        }
    }
}

// =====================================================================
// Kernel 2: sequential scan. One WG (256 threads, 4 waves) per batch row.
// Thread j caches W_hh row j in 256 VGPRs (launch_bounds(256,1) -> up to
// 512 VGPRs, 1 wave/SIMD). h ping-pongs in LDS; per step: 64 float4
// broadcast reads + 256 FMAs per thread, one barrier. fc head fused.
// =====================================================================
template <typename XWT>
__global__ __launch_bounds__(256, 1) void rnn_scan(const XWT* __restrict__ xw,
                                                   const float* __restrict__ W_hh,
                                                   const float* __restrict__ fc_w,
                                                   const float* __restrict__ fc_b,
                                                   float* __restrict__ out) {
    __shared__ __attribute__((aligned(16))) float hbuf[2][H_];
    __shared__ float red[H_];

    const int b = (int)blockIdx.x;
    const int j = (int)threadIdx.x;

    // W_hh row j -> registers (256 floats as 64 float4)
    float4 w4[64];
    const float4* wrow = reinterpret_cast<const float4*>(W_hh + (size_t)j * H_);
#pragma unroll
    for (int q = 0; q < 64; ++q) w4[q] = wrow[q];

    hbuf[0][j] = 0.f;
    __syncthreads();

    const XWT* xwp = xw + (size_t)b * T_ * H_ + j;
    float xw_next = xwt_to_float(xwp[0]);

    int cur = 0;
    for (int t = 0; t < T_; ++t) {
        float acc = xw_next;
        if (t + 1 < T_) xw_next = xwt_to_float(xwp[(size_t)(t + 1) * H_]);  // prefetch (independent of h)

        const float4* h4 = reinterpret_cast<const float4*>(hbuf[cur]);
#pragma unroll
        for (int q = 0; q < 64; ++q) {
            float4 hv = h4[q];
            acc = fmaf(hv.x, w4[q].x, acc);
            acc = fmaf(hv.y, w4[q].y, acc);
            acc = fmaf(hv.z, w4[q].z, acc);
            acc = fmaf(hv.w, w4[q].w, acc);
        }
        const float hn = tanhf(acc);
        hbuf[cur ^ 1][j] = hn;   // write buffer nobody reads this step
        __syncthreads();
        cur ^= 1;
    }

    // fc head: out[b] = dot(h_T, fc_w) + fc_b   (O = 1)
    red[j] = hbuf[cur][j] * fc_w[j];
    __syncthreads();
    for (int s = 128; s > 0; s >>= 1) {
        if (j < s) red[j] += red[j + s];
        __syncthreads();
    }
    if (j == 0) out[b] = red[0] + fc_b[0];
}

// =====================================================================
extern "C" void kernel_launch(void* const* d_in, const int* in_sizes, int n_in,
                              void* d_out, int out_size, void* d_ws, size_t ws_size,
                              hipStream_t stream) {
    const float* x    = (const float*)d_in[0];
    const float* W_ih = (const float*)d_in[1];
    const float* W_hh = (const float*)d_in[2];
    const float* b_ih = (const float*)d_in[3];
    const float* b_hh = (const float*)d_in[4];
    const float* fc_w = (const float*)d_in[5];
    const float* fc_b = (const float*)d_in[6];
    float* out = (float*)d_out;

    const int grid1 = (B_ * T_ / 128) * (H_ / 128);  // 1024 * 2 = 2048

    const size_t need_f32 = (size_t)B_ * T_ * H_ * sizeof(float);  // 134 MB
    if (ws_size >= need_f32) {
        float* xw = (float*)d_ws;
        xw_gemm<float><<<grid1, 256, 0, stream>>>(x, W_ih, b_ih, b_hh, xw);
        rnn_scan<float><<<B_, 256, 0, stream>>>(xw, W_hh, fc_w, fc_b, out);
    } else {
        // workspace too small for fp32 xw: store bf16 (67 MB)
        __hip_bfloat16* xw = (__hip_bfloat16*)d_ws;
        xw_gemm<__hip_bfloat16><<<grid1, 256, 0, stream>>>(x, W_ih, b_ih, b_hh, xw);
        rnn_scan<__hip_bfloat16><<<B_, 256, 0, stream>>>(xw, W_hh, fc_w, fc_b, out);
    }
}